// Round 17
// baseline (379.047 us; speedup 1.0000x reference)
//
#include <hip/hip_runtime.h>
#include <hip/hip_bf16.h>

#define B_ 4
#define H_ 16
#define L_ 2048
#define D_ 128
#define BH_ 64

typedef __attribute__((ext_vector_type(8))) _Float16 f16x8;
typedef __attribute__((ext_vector_type(4))) float f32x4;
typedef __attribute__((ext_vector_type(16))) float f32x16;
typedef __attribute__((ext_vector_type(2))) unsigned u32x2;

#define L2E 1.44269504088896f

// gm = L2E*gelu(v) + negm, tanh-form GELU (|err vs exact-erf gelu| ~3e-4):
// 9 VALU ops; verified absmax-neutral in R15.
__device__ __forceinline__ float gelu_m(float v, float negm) {
  float u  = v * v;
  float m1 = 0.044715f * u;
  float w  = __builtin_fmaf(m1, v, v);             // v + 0.044715 v^3
  float e  = __builtin_amdgcn_exp2f(-2.3020575f * w); // exp2(-2*0.79788*L2E*w)
  float r  = __builtin_amdgcn_rcpf(1.0f + e);      // sigmoid
  float t  = 1.44269504f * v;
  return __builtin_fmaf(t, r, negm);               // L2E*gelu(v) + negm
}

__device__ __forceinline__ void gl2lds16(const void* g, void* l) {
  __builtin_amdgcn_global_load_lds(
      (const __attribute__((address_space(1))) void*)g,
      (__attribute__((address_space(3))) void*)l, 16, 0, 0);
}

__device__ __forceinline__ unsigned pkrtz(float a, float b) {
  auto t = __builtin_amdgcn_cvt_pkrtz(a, b);   // __fp16 ext_vector(2)
  return __builtin_bit_cast(unsigned, t);
}

// ---------------------------------------------------------------------------
// Kernel 0: one-time W1,W2 f32 -> f16 (scratch in d_out head; attn overwrites).
// ---------------------------------------------------------------------------
__global__ __launch_bounds__(256) void wcvt_kernel(
    const float* __restrict__ W1, const float* __restrict__ W2,
    _Float16* __restrict__ Wh1, _Float16* __restrict__ Wh2)
{
  int i = blockIdx.x * 256 + threadIdx.x;
  Wh1[i] = (_Float16)W1[i];
  Wh2[i] = (_Float16)W2[i];
}

// ---------------------------------------------------------------------------
// Kernel 1: q/k projections (f16 MFMA, f32 accum, +bias) and x -> V^T (f16).
// R17: A-fragment x loads vectorized to float4 (8 dwordx4 vs 32 scalar) +
// cvt_pkrtz packing (4 cvt vs 8 per fragment).
// ---------------------------------------------------------------------------
__global__ __launch_bounds__(256) void proj_tr_kernel(
    const float* __restrict__ x,
    const _Float16* __restrict__ Wh1, const float* __restrict__ b1,
    const _Float16* __restrict__ Wh2, const float* __restrict__ b2,
    _Float16* __restrict__ Qb, _Float16* __restrict__ Kb,
    _Float16* __restrict__ VT)
{
  const int tid  = threadIdx.x;
  const int wave = tid >> 6;
  const int lane = tid & 63;
  const int lhi  = lane >> 4;
  const int llo  = lane & 15;
  const int r0   = blockIdx.x * 64;
  const int wr0  = r0 + wave * 16;

  f16x8 a[4];
#pragma unroll
  for (int ks = 0; ks < 4; ++ks) {
    const f32x4* p = (const f32x4*)(x + (size_t)(wr0 + llo) * D_ + lhi * 8 + ks * 32);
    f32x4 f0 = p[0], f1 = p[1];
    union { unsigned u[4]; f16x8 v; } t;
    t.u[0] = pkrtz(f0[0], f0[1]);
    t.u[1] = pkrtz(f0[2], f0[3]);
    t.u[2] = pkrtz(f1[0], f1[1]);
    t.u[3] = pkrtz(f1[2], f1[3]);
    a[ks] = t.v;
  }

  f32x4 accq[8], acck[8];
#pragma unroll
  for (int n = 0; n < 8; ++n) {
    accq[n] = (f32x4){0.f, 0.f, 0.f, 0.f};
    acck[n] = (f32x4){0.f, 0.f, 0.f, 0.f};
  }

#pragma unroll
  for (int n = 0; n < 8; ++n) {
    const int e = n * 16 + llo;
#pragma unroll
    for (int ks = 0; ks < 4; ++ks) {
      f16x8 w1f = *(const f16x8*)(Wh1 + (size_t)e * D_ + lhi * 8 + ks * 32);
      f16x8 w2f = *(const f16x8*)(Wh2 + (size_t)e * D_ + lhi * 8 + ks * 32);
      accq[n] = __builtin_amdgcn_mfma_f32_16x16x32_f16(a[ks], w1f, accq[n], 0, 0, 0);
      acck[n] = __builtin_amdgcn_mfma_f32_16x16x32_f16(a[ks], w2f, acck[n], 0, 0, 0);
    }
  }

#pragma unroll
  for (int n = 0; n < 8; ++n) {
    const int e = n * 16 + llo;
    const float bias1 = b1[e];
    const float bias2 = b2[e];
#pragma unroll
    for (int r = 0; r < 4; ++r) {
      const size_t row = (size_t)wr0 + lhi * 4 + r;
      Qb[row * D_ + e] = (_Float16)(accq[n][r] + bias1);
      Kb[row * D_ + e] = (_Float16)(acck[n][r] + bias2);
    }
  }

  const int bh = r0 / L_;
  const int l0 = r0 % L_;
  const int d  = tid & 127;
  const int rh = tid >> 7;
  _Float16* dst = VT + (size_t)bh * D_ * L_ + (size_t)d * L_ + l0 + rh * 32;
#pragma unroll
  for (int j = 0; j < 4; ++j) {
    f16x8 t;
#pragma unroll
    for (int e = 0; e < 8; ++e)
      t[e] = (_Float16)x[(size_t)(r0 + rh * 32 + j * 8 + e) * D_ + d];
    *(f16x8*)(dst + j * 8) = t;
  }
}

// ---------------------------------------------------------------------------
// Kernel 2: fused gelu(QK^T)->softmax->@V flash attention, 32x32x16 MFMA.
// R16 structure (K+V [128][128] supertiles, 16 barriers, 4-bit swizzle,
// conflicts=0, deferred l-sum) + R17 delta: PAIR-MERGED softmax guard --
// gelu both subtiles (32 chains, batched TRANS ops), one max tree, ONE
// cross-half shuffle + __all + branch + rescale per tile (was 2).
// R14 lesson: NO cross-tile score pipelining (extra f32x16 sets spill).
// ---------------------------------------------------------------------------
__global__ __launch_bounds__(512) void attn_kernel(
    const _Float16* __restrict__ Qb, const _Float16* __restrict__ Kb,
    const _Float16* __restrict__ VT, float* __restrict__ out)
{
  __shared__ _Float16 Ks[2][128 * 128];   // 2 x 32KB, K supertile (128 k-rows)
  __shared__ _Float16 Vs[2][128 * 128];   // 2 x 32KB, V supertile (128 k)

  const int tid  = threadIdx.x;
  const int wave = tid >> 6;      // 0..7
  const int lane = tid & 63;
  const int l5   = lane & 31;
  const int hi   = lane >> 5;

  // XCD-aware swizzle: 512 blocks, 8 XCDs -> 8 whole heads per XCD.
  const int bid = blockIdx.x;
  const int blk = (bid & 7) * 64 + (bid >> 3);
  const int bh  = blk >> 3;            // 8 q-blocks (256 rows) per head
  const int q0  = (blk & 7) * 256;
  const int b   = bh >> 4;
  const int h   = bh & 15;
  const int wq0 = q0 + wave * 32;

  const char* KheadB = (const char*)(Kb + (size_t)bh * L_ * D_);
  const char* VheadB = (const char*)(VT + (size_t)bh * D_ * L_);

  // ---- staging constants: K and V supertiles, 4 calls x 8KB each ----
  int sdst[4], ksrc[4], vsrc[4];
#pragma unroll
  for (int c = 0; c < 4; ++c) {
    const int row = c * 32 + wave * 4 + (lane >> 4);    // 0..127
    const int c0  = (lane & 15) * 8;                    // col halves
    sdst[c] = c * 8192 + wave * 1024;                   // wave-uniform dest
    ksrc[c] = row * 256  + 2 * (c0 ^ ((row & 15) << 3)); // K row = 256B
    vsrc[c] = row * 4096 + 2 * (c0 ^ ((row & 15) << 3)); // V row = L*2B
  }
  const int swz4 = (l5 & 15) << 3;                      // read-side XOR (halves)

  // Q fragments (B-operand of swapped QK^T): j = l5 = q-row, k = s*16+hi*8+e
  f16x8 qf[8];
#pragma unroll
  for (int s = 0; s < 8; ++s)
    qf[s] = *(const f16x8*)(Qb + ((size_t)bh * L_ + wq0 + l5) * D_ + s * 16 + hi * 8);

  f32x16 accO[4];
#pragma unroll
  for (int n = 0; n < 4; ++n)
#pragma unroll
    for (int r = 0; r < 16; ++r) accO[n][r] = 0.f;
  float negm = 64.f;   // -m in exp2 units; m init -64 (synced across hi pair)
  float l = 0.f;       // per-half partial sum; combined once at epilogue

  // ---- prologue: stage K/V supertile 0 ----
#pragma unroll
  for (int c = 0; c < 4; ++c) {
    gl2lds16(KheadB + ksrc[c], (char*)&Ks[0][0] + sdst[c]);
    gl2lds16(VheadB + vsrc[c], (char*)&Vs[0][0] + sdst[c]);
  }
  __syncthreads();

  for (int ts = 0; ts < L_ / 128; ++ts) {   // 16 supertiles, 1 barrier each
    const int cur = ts & 1;
    // ---- prefetch next K/V supertile (in flight across 2 tile bodies) ----
    if (ts + 1 < L_ / 128) {
      const char* kt_ = KheadB + (size_t)(ts + 1) * 32768;
      const char* vt_ = VheadB + (size_t)(ts + 1) * 256;
#pragma unroll
      for (int c = 0; c < 4; ++c) {
        gl2lds16(kt_ + ksrc[c], (char*)&Ks[cur ^ 1][0] + sdst[c]);
        gl2lds16(vt_ + vsrc[c], (char*)&Vs[cur ^ 1][0] + sdst[c]);
      }
    }
    const _Float16* Vcur = &Vs[cur][0];

#pragma unroll
    for (int half = 0; half < 2; ++half) {   // two 64-k tiles per supertile
      const _Float16* Kcur = &Ks[cur][half * 64 * 128];
      const int vt0 = half * 64;             // k-offset in V supertile

      // ---- S^T for BOTH kb subtiles: two interleaved 8-deep chains ----
      f32x16 sA, sB;
#pragma unroll
      for (int r = 0; r < 16; ++r) { sA[r] = 0.f; sB[r] = 0.f; }
      __builtin_amdgcn_s_setprio(1);
#pragma unroll
      for (int s = 0; s < 8; ++s) {
        f16x8 kfa = *(const f16x8*)(Kcur + l5 * 128 +
                                    ((s * 16 + hi * 8) ^ swz4));
        sA = __builtin_amdgcn_mfma_f32_32x32x16_f16(kfa, qf[s], sA, 0, 0, 0);
        f16x8 kfb = *(const f16x8*)(Kcur + (32 + l5) * 128 +
                                    ((s * 16 + hi * 8) ^ swz4));
        sB = __builtin_amdgcn_mfma_f32_32x32x16_f16(kfb, qf[s], sB, 0, 0, 0);
      }
      __builtin_amdgcn_s_setprio(0);

      // ---- PAIR-MERGED gelu + guard: 32 chains, one tree, one shuffle ----
      float gmA[16], gmB[16];
#pragma unroll
      for (int r = 0; r < 16; ++r) {
        gmA[r] = gelu_m(sA[r], negm);
        gmB[r] = gelu_m(sB[r], negm);
      }
      float tm = fmaxf(gmA[0], gmB[0]);
#pragma unroll
      for (int r = 1; r < 16; ++r)
        tm = fmaxf(tm, fmaxf(gmA[r], gmB[r]));
      tm = fmaxf(tm, __shfl_xor(tm, 32));   // REQUIRED: negm shared by pair

      float pA[16], pB[16];
      if (__all(tm <= 11.5415603f)) {
#pragma unroll
        for (int r = 0; r < 16; ++r) {
          pA[r] = __builtin_amdgcn_exp2f(gmA[r]);
          pB[r] = __builtin_amdgcn_exp2f(gmB[r]);
        }
        float a0 = pA[0]+pA[1],   a1 = pA[2]+pA[3],   a2 = pA[4]+pA[5],   a3 = pA[6]+pA[7];
        float a4 = pA[8]+pA[9],   a5 = pA[10]+pA[11], a6 = pA[12]+pA[13], a7 = pA[14]+pA[15];
        float b0 = pB[0]+pB[1],   b1_ = pB[2]+pB[3],  b2_ = pB[4]+pB[5],  b3 = pB[6]+pB[7];
        float b4 = pB[8]+pB[9],   b5 = pB[10]+pB[11], b6 = pB[12]+pB[13], b7 = pB[14]+pB[15];
        l += (((a0+a1)+(a2+a3)) + ((a4+a5)+(a6+a7))) +
             (((b0+b1_)+(b2_+b3)) + ((b4+b5)+(b6+b7)));
      } else {
        float dm = fmaxf(tm, 0.f);
        negm -= dm;
        float sc = __builtin_amdgcn_exp2f(-dm);
#pragma unroll
        for (int r = 0; r < 16; ++r) {
          pA[r] = __builtin_amdgcn_exp2f(gmA[r] - dm);
          pB[r] = __builtin_amdgcn_exp2f(gmB[r] - dm);
        }
        float a0 = pA[0]+pA[1],   a1 = pA[2]+pA[3],   a2 = pA[4]+pA[5],   a3 = pA[6]+pA[7];
        float a4 = pA[8]+pA[9],   a5 = pA[10]+pA[11], a6 = pA[12]+pA[13], a7 = pA[14]+pA[15];
        float b0 = pB[0]+pB[1],   b1_ = pB[2]+pB[3],  b2_ = pB[4]+pB[5],  b3 = pB[6]+pB[7];
        float b4 = pB[8]+pB[9],   b5 = pB[10]+pB[11], b6 = pB[12]+pB[13], b7 = pB[14]+pB[15];
        float ts_ = (((a0+a1)+(a2+a3)) + ((a4+a5)+(a6+a7))) +
                    (((b0+b1_)+(b2_+b3)) + ((b4+b5)+(b6+b7)));
        l = __builtin_fmaf(l, sc, ts_);      // sc uniform across pair
        float scr[16];
#pragma unroll
        for (int r = 0; r < 16; ++r)
          scr[r] = __shfl(sc, (r & 3) + 8 * (r >> 2) + 4 * hi);
#pragma unroll
        for (int n = 0; n < 4; ++n)
#pragma unroll
          for (int r = 0; r < 16; ++r) accO[n][r] *= scr[r];
      }

      // ---- PV per subtile (T12 in-reg P->A-frag; distinct operands) ----
      auto pv = [&](const float* p, int vkbase) {
        unsigned pk01 = pkrtz(p[0], p[1]),   pk23 = pkrtz(p[2], p[3]);
        unsigned pk45 = pkrtz(p[4], p[5]),   pk67 = pkrtz(p[6], p[7]);
        unsigned pk89 = pkrtz(p[8], p[9]),   pkAB = pkrtz(p[10], p[11]);
        unsigned pkCD = pkrtz(p[12], p[13]), pkEF = pkrtz(p[14], p[15]);
        u32x2 r0 = __builtin_amdgcn_permlane32_swap(pk01, pk45, false, false);
        u32x2 r1 = __builtin_amdgcn_permlane32_swap(pk23, pk67, false, false);
        u32x2 r2 = __builtin_amdgcn_permlane32_swap(pk89, pkCD, false, false);
        u32x2 r3 = __builtin_amdgcn_permlane32_swap(pkAB, pkEF, false, false);
        union { unsigned u[4]; f16x8 v; } A0c, A1c;
        A0c.u[0] = r0[0]; A0c.u[1] = r1[0]; A0c.u[2] = r0[1]; A0c.u[3] = r1[1];
        A1c.u[0] = r2[0]; A1c.u[1] = r3[0]; A1c.u[2] = r2[1]; A1c.u[3] = r3[1];

        __builtin_amdgcn_s_setprio(1);
#pragma unroll
        for (int n = 0; n < 4; ++n) {
          f16x8 vf0 = *(const f16x8*)(Vcur + (n * 32 + l5) * 128 +
                                      ((vkbase + hi * 8) ^ swz4));
          accO[n] = __builtin_amdgcn_mfma_f32_32x32x16_f16(A0c.v, vf0, accO[n], 0, 0, 0);
          f16x8 vf1 = *(const f16x8*)(Vcur + (n * 32 + l5) * 128 +
                                      ((vkbase + 16 + hi * 8) ^ swz4));
          accO[n] = __builtin_amdgcn_mfma_f32_32x32x16_f16(A1c.v, vf1, accO[n], 0, 0, 0);
        }
        __builtin_amdgcn_s_setprio(0);
      };

      pv(pA, vt0);
      pv(pB, vt0 + 32);
    }

    __syncthreads();   // one barrier per supertile (2 tiles); prefetch landed
  }

  // ---- epilogue: combine per-half l, then O[q][d] / l[q] ----
  l += __shfl_xor(l, 32);                    // the single cross-half l sum
  float linv = __builtin_amdgcn_rcpf(l);
  float lb[16];
#pragma unroll
  for (int r = 0; r < 16; ++r)
    lb[r] = __shfl(linv, (r & 3) + 8 * (r >> 2) + 4 * hi);
#pragma unroll
  for (int n = 0; n < 4; ++n)
#pragma unroll
    for (int r = 0; r < 16; ++r) {
      const int i = wq0 + (r & 3) + 8 * (r >> 2) + 4 * hi;
      out[((size_t)(b * L_ + i) * H_ + h) * D_ + n * 32 + l5] = accO[n][r] * lb[r];
    }
}

extern "C" void kernel_launch(void* const* d_in, const int* in_sizes, int n_in,
                              void* d_out, int out_size, void* d_ws, size_t ws_size,
                              hipStream_t stream) {
  const float* x  = (const float*)d_in[0];
  const float* W1 = (const float*)d_in[1];
  const float* b1 = (const float*)d_in[2];
  const float* W2 = (const float*)d_in[3];
  const float* b2 = (const float*)d_in[4];
  float* out = (float*)d_out;

  const size_t N = (size_t)BH_ * L_ * D_;
  _Float16* Qb = (_Float16*)d_ws;
  _Float16* Kb = Qb + N;
  _Float16* VT = Kb + N;

  _Float16* Wh1 = (_Float16*)d_out;          // scratch; attn overwrites out
  _Float16* Wh2 = Wh1 + D_ * D_;

  wcvt_kernel<<<64, 256, 0, stream>>>(W1, W2, Wh1, Wh2);
  proj_tr_kernel<<<(BH_ * L_) / 64, 256, 0, stream>>>(x, Wh1, b1, Wh2, b2, Qb, Kb, VT);
  attn_kernel<<<BH_ * (L_ / 256), 512, 0, stream>>>(Qb, Kb, VT, out);
}

// Round 18
// 338.486 us; speedup vs baseline: 1.1198x; 1.1198x over previous
//
#include <hip/hip_runtime.h>
#include <hip/hip_bf16.h>

#define B_ 4
#define H_ 16
#define L_ 2048
#define D_ 128
#define BH_ 64

typedef __attribute__((ext_vector_type(8))) _Float16 f16x8;
typedef __attribute__((ext_vector_type(4))) float f32x4;
typedef __attribute__((ext_vector_type(16))) float f32x16;
typedef __attribute__((ext_vector_type(2))) unsigned u32x2;

#define L2E 1.44269504088896f

// gm = L2E*gelu(v) + negm, tanh-form GELU (|err vs exact-erf gelu| ~3e-4):
// 9 VALU ops; verified absmax-neutral in R15.
__device__ __forceinline__ float gelu_m(float v, float negm) {
  float u  = v * v;
  float m1 = 0.044715f * u;
  float w  = __builtin_fmaf(m1, v, v);             // v + 0.044715 v^3
  float e  = __builtin_amdgcn_exp2f(-2.3020575f * w); // exp2(-2*0.79788*L2E*w)
  float r  = __builtin_amdgcn_rcpf(1.0f + e);      // sigmoid
  float t  = 1.44269504f * v;
  return __builtin_fmaf(t, r, negm);               // L2E*gelu(v) + negm
}

__device__ __forceinline__ void gl2lds16(const void* g, void* l) {
  __builtin_amdgcn_global_load_lds(
      (const __attribute__((address_space(1))) void*)g,
      (__attribute__((address_space(3))) void*)l, 16, 0, 0);
}

__device__ __forceinline__ unsigned pkrtz(float a, float b) {
  auto t = __builtin_amdgcn_cvt_pkrtz(a, b);   // __fp16 ext_vector(2)
  return __builtin_bit_cast(unsigned, t);
}

// ---------------------------------------------------------------------------
// Kernel 0: one-time W1,W2 f32 -> f16 (scratch in d_out head; attn overwrites).
// ---------------------------------------------------------------------------
__global__ __launch_bounds__(256) void wcvt_kernel(
    const float* __restrict__ W1, const float* __restrict__ W2,
    _Float16* __restrict__ Wh1, _Float16* __restrict__ Wh2)
{
  int i = blockIdx.x * 256 + threadIdx.x;
  Wh1[i] = (_Float16)W1[i];
  Wh2[i] = (_Float16)W2[i];
}

// ---------------------------------------------------------------------------
// Kernel 1: q/k projections (f16 MFMA, f32 accum, +bias) and x -> V^T (f16).
// R17 keeper: A-fragment x loads vectorized to float4 + cvt_pkrtz packing
// (non-attn time 79 -> 65 us).
// ---------------------------------------------------------------------------
__global__ __launch_bounds__(256) void proj_tr_kernel(
    const float* __restrict__ x,
    const _Float16* __restrict__ Wh1, const float* __restrict__ b1,
    const _Float16* __restrict__ Wh2, const float* __restrict__ b2,
    _Float16* __restrict__ Qb, _Float16* __restrict__ Kb,
    _Float16* __restrict__ VT)
{
  const int tid  = threadIdx.x;
  const int wave = tid >> 6;
  const int lane = tid & 63;
  const int lhi  = lane >> 4;
  const int llo  = lane & 15;
  const int r0   = blockIdx.x * 64;
  const int wr0  = r0 + wave * 16;

  f16x8 a[4];
#pragma unroll
  for (int ks = 0; ks < 4; ++ks) {
    const f32x4* p = (const f32x4*)(x + (size_t)(wr0 + llo) * D_ + lhi * 8 + ks * 32);
    f32x4 f0 = p[0], f1 = p[1];
    union { unsigned u[4]; f16x8 v; } t;
    t.u[0] = pkrtz(f0[0], f0[1]);
    t.u[1] = pkrtz(f0[2], f0[3]);
    t.u[2] = pkrtz(f1[0], f1[1]);
    t.u[3] = pkrtz(f1[2], f1[3]);
    a[ks] = t.v;
  }

  f32x4 accq[8], acck[8];
#pragma unroll
  for (int n = 0; n < 8; ++n) {
    accq[n] = (f32x4){0.f, 0.f, 0.f, 0.f};
    acck[n] = (f32x4){0.f, 0.f, 0.f, 0.f};
  }

#pragma unroll
  for (int n = 0; n < 8; ++n) {
    const int e = n * 16 + llo;
#pragma unroll
    for (int ks = 0; ks < 4; ++ks) {
      f16x8 w1f = *(const f16x8*)(Wh1 + (size_t)e * D_ + lhi * 8 + ks * 32);
      f16x8 w2f = *(const f16x8*)(Wh2 + (size_t)e * D_ + lhi * 8 + ks * 32);
      accq[n] = __builtin_amdgcn_mfma_f32_16x16x32_f16(a[ks], w1f, accq[n], 0, 0, 0);
      acck[n] = __builtin_amdgcn_mfma_f32_16x16x32_f16(a[ks], w2f, acck[n], 0, 0, 0);
    }
  }

#pragma unroll
  for (int n = 0; n < 8; ++n) {
    const int e = n * 16 + llo;
    const float bias1 = b1[e];
    const float bias2 = b2[e];
#pragma unroll
    for (int r = 0; r < 4; ++r) {
      const size_t row = (size_t)wr0 + lhi * 4 + r;
      Qb[row * D_ + e] = (_Float16)(accq[n][r] + bias1);
      Kb[row * D_ + e] = (_Float16)(acck[n][r] + bias2);
    }
  }

  const int bh = r0 / L_;
  const int l0 = r0 % L_;
  const int d  = tid & 127;
  const int rh = tid >> 7;
  _Float16* dst = VT + (size_t)bh * D_ * L_ + (size_t)d * L_ + l0 + rh * 32;
#pragma unroll
  for (int j = 0; j < 4; ++j) {
    f16x8 t;
#pragma unroll
    for (int e = 0; e < 8; ++e)
      t[e] = (_Float16)x[(size_t)(r0 + rh * 32 + j * 8 + e) * D_ + d];
    *(f16x8*)(dst + j * 8) = t;
  }
}

// ---------------------------------------------------------------------------
// Kernel 2: fused gelu(QK^T)->softmax->@V flash attention, 32x32x16 MFMA.
// R16 attn VERBATIM (best measured 270.5us): K+V [128][128] supertiles,
// 16 barriers, 4-bit swizzle (conflicts=0), per-subtile softmax (16-float
// liveness), deferred l-sum, T15 within-tile pipeline, T12, defer-max.
// R17 lesson: pair-merged softmax (32-float liveness) spills -> reverted.
// R14 lesson: NO cross-tile score pipelining (extra f32x16 sets spill).
// ---------------------------------------------------------------------------
__global__ __launch_bounds__(512) void attn_kernel(
    const _Float16* __restrict__ Qb, const _Float16* __restrict__ Kb,
    const _Float16* __restrict__ VT, float* __restrict__ out)
{
  __shared__ _Float16 Ks[2][128 * 128];   // 2 x 32KB, K supertile (128 k-rows)
  __shared__ _Float16 Vs[2][128 * 128];   // 2 x 32KB, V supertile (128 k)

  const int tid  = threadIdx.x;
  const int wave = tid >> 6;      // 0..7
  const int lane = tid & 63;
  const int l5   = lane & 31;
  const int hi   = lane >> 5;

  // XCD-aware swizzle: 512 blocks, 8 XCDs -> 8 whole heads per XCD.
  const int bid = blockIdx.x;
  const int blk = (bid & 7) * 64 + (bid >> 3);
  const int bh  = blk >> 3;            // 8 q-blocks (256 rows) per head
  const int q0  = (blk & 7) * 256;
  const int b   = bh >> 4;
  const int h   = bh & 15;
  const int wq0 = q0 + wave * 32;

  const char* KheadB = (const char*)(Kb + (size_t)bh * L_ * D_);
  const char* VheadB = (const char*)(VT + (size_t)bh * D_ * L_);

  // ---- staging constants: K and V supertiles, 4 calls x 8KB each ----
  int sdst[4], ksrc[4], vsrc[4];
#pragma unroll
  for (int c = 0; c < 4; ++c) {
    const int row = c * 32 + wave * 4 + (lane >> 4);    // 0..127
    const int c0  = (lane & 15) * 8;                    // col halves
    sdst[c] = c * 8192 + wave * 1024;                   // wave-uniform dest
    ksrc[c] = row * 256  + 2 * (c0 ^ ((row & 15) << 3)); // K row = 256B
    vsrc[c] = row * 4096 + 2 * (c0 ^ ((row & 15) << 3)); // V row = L*2B
  }
  const int swz4 = (l5 & 15) << 3;                      // read-side XOR (halves)

  // Q fragments (B-operand of swapped QK^T): j = l5 = q-row, k = s*16+hi*8+e
  f16x8 qf[8];
#pragma unroll
  for (int s = 0; s < 8; ++s)
    qf[s] = *(const f16x8*)(Qb + ((size_t)bh * L_ + wq0 + l5) * D_ + s * 16 + hi * 8);

  f32x16 accO[4];
#pragma unroll
  for (int n = 0; n < 4; ++n)
#pragma unroll
    for (int r = 0; r < 16; ++r) accO[n][r] = 0.f;
  float negm = 64.f;   // -m in exp2 units; m init -64 (synced across hi pair)
  float l = 0.f;       // per-half partial sum; combined once at epilogue

  // ---- prologue: stage K/V supertile 0 ----
#pragma unroll
  for (int c = 0; c < 4; ++c) {
    gl2lds16(KheadB + ksrc[c], (char*)&Ks[0][0] + sdst[c]);
    gl2lds16(VheadB + vsrc[c], (char*)&Vs[0][0] + sdst[c]);
  }
  __syncthreads();

  for (int ts = 0; ts < L_ / 128; ++ts) {   // 16 supertiles, 1 barrier each
    const int cur = ts & 1;
    // ---- prefetch next K/V supertile (in flight across 2 tile bodies) ----
    if (ts + 1 < L_ / 128) {
      const char* kt_ = KheadB + (size_t)(ts + 1) * 32768;
      const char* vt_ = VheadB + (size_t)(ts + 1) * 256;
#pragma unroll
      for (int c = 0; c < 4; ++c) {
        gl2lds16(kt_ + ksrc[c], (char*)&Ks[cur ^ 1][0] + sdst[c]);
        gl2lds16(vt_ + vsrc[c], (char*)&Vs[cur ^ 1][0] + sdst[c]);
      }
    }
    const _Float16* Vcur = &Vs[cur][0];

#pragma unroll
    for (int half = 0; half < 2; ++half) {   // two 64-k tiles per supertile
      const _Float16* Kcur = &Ks[cur][half * 64 * 128];
      const int vt0 = half * 64;             // k-offset in V supertile

      // ---- S^T for BOTH kb subtiles: two interleaved 8-deep chains ----
      f32x16 sA, sB;
#pragma unroll
      for (int r = 0; r < 16; ++r) { sA[r] = 0.f; sB[r] = 0.f; }
      __builtin_amdgcn_s_setprio(1);
#pragma unroll
      for (int s = 0; s < 8; ++s) {
        f16x8 kfa = *(const f16x8*)(Kcur + l5 * 128 +
                                    ((s * 16 + hi * 8) ^ swz4));
        sA = __builtin_amdgcn_mfma_f32_32x32x16_f16(kfa, qf[s], sA, 0, 0, 0);
        f16x8 kfb = *(const f16x8*)(Kcur + (32 + l5) * 128 +
                                    ((s * 16 + hi * 8) ^ swz4));
        sB = __builtin_amdgcn_mfma_f32_32x32x16_f16(kfb, qf[s], sB, 0, 0, 0);
      }
      __builtin_amdgcn_s_setprio(0);

      // ---- softmax + PV per subtile ----
      auto softmax_pv = [&](const f32x16& sT, int vkbase) {
        float gm[16];
#pragma unroll
        for (int r = 0; r < 16; ++r) gm[r] = gelu_m(sT[r], negm);

        float tm = fmaxf(fmaxf(gm[0], gm[1]), gm[2]);
        tm = fmaxf(fmaxf(tm, gm[3]),  gm[4]);
        tm = fmaxf(fmaxf(tm, gm[5]),  gm[6]);
        tm = fmaxf(fmaxf(tm, gm[7]),  gm[8]);
        tm = fmaxf(fmaxf(tm, gm[9]),  gm[10]);
        tm = fmaxf(fmaxf(tm, gm[11]), gm[12]);
        tm = fmaxf(fmaxf(tm, gm[13]), gm[14]);
        tm = fmaxf(tm, gm[15]);
        tm = fmaxf(tm, __shfl_xor(tm, 32));   // REQUIRED: negm shared by pair

        float p[16];
        float ts_;
        if (__all(tm <= 11.5415603f)) {
#pragma unroll
          for (int r = 0; r < 16; ++r) p[r] = __builtin_amdgcn_exp2f(gm[r]);
          float a0 = p[0]+p[1],   a1 = p[2]+p[3],   a2 = p[4]+p[5],   a3 = p[6]+p[7];
          float a4 = p[8]+p[9],   a5 = p[10]+p[11], a6 = p[12]+p[13], a7 = p[14]+p[15];
          ts_ = ((a0+a1)+(a2+a3)) + ((a4+a5)+(a6+a7));
          l += ts_;                            // per-half partial
        } else {
          float dm = fmaxf(tm, 0.f);
          negm -= dm;
          float sc = __builtin_amdgcn_exp2f(-dm);
#pragma unroll
          for (int r = 0; r < 16; ++r) p[r] = __builtin_amdgcn_exp2f(gm[r] - dm);
          float a0 = p[0]+p[1],   a1 = p[2]+p[3],   a2 = p[4]+p[5],   a3 = p[6]+p[7];
          float a4 = p[8]+p[9],   a5 = p[10]+p[11], a6 = p[12]+p[13], a7 = p[14]+p[15];
          ts_ = ((a0+a1)+(a2+a3)) + ((a4+a5)+(a6+a7));
          l = __builtin_fmaf(l, sc, ts_);      // sc uniform across pair
          float scr[16];
#pragma unroll
          for (int r = 0; r < 16; ++r)
            scr[r] = __shfl(sc, (r & 3) + 8 * (r >> 2) + 4 * hi);
#pragma unroll
          for (int n = 0; n < 4; ++n)
#pragma unroll
            for (int r = 0; r < 16; ++r) accO[n][r] *= scr[r];
        }

        // P -> PV A-fragments in-register (T12; distinct operands only)
        unsigned pk01 = pkrtz(p[0], p[1]),   pk23 = pkrtz(p[2], p[3]);
        unsigned pk45 = pkrtz(p[4], p[5]),   pk67 = pkrtz(p[6], p[7]);
        unsigned pk89 = pkrtz(p[8], p[9]),   pkAB = pkrtz(p[10], p[11]);
        unsigned pkCD = pkrtz(p[12], p[13]), pkEF = pkrtz(p[14], p[15]);
        u32x2 r0 = __builtin_amdgcn_permlane32_swap(pk01, pk45, false, false);
        u32x2 r1 = __builtin_amdgcn_permlane32_swap(pk23, pk67, false, false);
        u32x2 r2 = __builtin_amdgcn_permlane32_swap(pk89, pkCD, false, false);
        u32x2 r3 = __builtin_amdgcn_permlane32_swap(pkAB, pkEF, false, false);
        union { unsigned u[4]; f16x8 v; } A0c, A1c;
        A0c.u[0] = r0[0]; A0c.u[1] = r1[0]; A0c.u[2] = r0[1]; A0c.u[3] = r1[1];
        A1c.u[0] = r2[0]; A1c.u[1] = r3[0]; A1c.u[2] = r2[1]; A1c.u[3] = r3[1];

        // O += P @ V (V rows 128 halves in the supertile)
        __builtin_amdgcn_s_setprio(1);
#pragma unroll
        for (int n = 0; n < 4; ++n) {
          f16x8 vf0 = *(const f16x8*)(Vcur + (n * 32 + l5) * 128 +
                                      ((vkbase + hi * 8) ^ swz4));
          accO[n] = __builtin_amdgcn_mfma_f32_32x32x16_f16(A0c.v, vf0, accO[n], 0, 0, 0);
          f16x8 vf1 = *(const f16x8*)(Vcur + (n * 32 + l5) * 128 +
                                      ((vkbase + 16 + hi * 8) ^ swz4));
          accO[n] = __builtin_amdgcn_mfma_f32_32x32x16_f16(A1c.v, vf1, accO[n], 0, 0, 0);
        }
        __builtin_amdgcn_s_setprio(0);
      };

      softmax_pv(sA, vt0);
      softmax_pv(sB, vt0 + 32);
    }

    __syncthreads();   // one barrier per supertile (2 tiles); prefetch landed
  }

  // ---- epilogue: combine per-half l, then O[q][d] / l[q] ----
  l += __shfl_xor(l, 32);                    // the single cross-half l sum
  float linv = __builtin_amdgcn_rcpf(l);
  float lb[16];
#pragma unroll
  for (int r = 0; r < 16; ++r)
    lb[r] = __shfl(linv, (r & 3) + 8 * (r >> 2) + 4 * hi);
#pragma unroll
  for (int n = 0; n < 4; ++n)
#pragma unroll
    for (int r = 0; r < 16; ++r) {
      const int i = wq0 + (r & 3) + 8 * (r >> 2) + 4 * hi;
      out[((size_t)(b * L_ + i) * H_ + h) * D_ + n * 32 + l5] = accO[n][r] * lb[r];
    }
}

extern "C" void kernel_launch(void* const* d_in, const int* in_sizes, int n_in,
                              void* d_out, int out_size, void* d_ws, size_t ws_size,
                              hipStream_t stream) {
  const float* x  = (const float*)d_in[0];
  const float* W1 = (const float*)d_in[1];
  const float* b1 = (const float*)d_in[2];
  const float* W2 = (const float*)d_in[3];
  const float* b2 = (const float*)d_in[4];
  float* out = (float*)d_out;

  const size_t N = (size_t)BH_ * L_ * D_;
  _Float16* Qb = (_Float16*)d_ws;
  _Float16* Kb = Qb + N;
  _Float16* VT = Kb + N;

  _Float16* Wh1 = (_Float16*)d_out;          // scratch; attn overwrites out
  _Float16* Wh2 = Wh1 + D_ * D_;

  wcvt_kernel<<<64, 256, 0, stream>>>(W1, W2, Wh1, Wh2);
  proj_tr_kernel<<<(BH_ * L_) / 64, 256, 0, stream>>>(x, Wh1, b1, Wh2, b2, Qb, Kb, VT);
  attn_kernel<<<BH_ * (L_ / 256), 512, 0, stream>>>(Qb, Kb, VT, out);
}

// Round 19
// 328.385 us; speedup vs baseline: 1.1543x; 1.0308x over previous
//
#include <hip/hip_runtime.h>
#include <hip/hip_bf16.h>

#define B_ 4
#define H_ 16
#define L_ 2048
#define D_ 128
#define BH_ 64

typedef __attribute__((ext_vector_type(8))) _Float16 f16x8;
typedef __attribute__((ext_vector_type(4))) float f32x4;
typedef __attribute__((ext_vector_type(16))) float f32x16;
typedef __attribute__((ext_vector_type(2))) unsigned u32x2;

#define L2E 1.44269504088896f

// gm = L2E*gelu(v) + negm, tanh-form GELU (|err vs exact-erf gelu| ~3e-4):
// 9 VALU ops; verified absmax-neutral in R15.
__device__ __forceinline__ float gelu_m(float v, float negm) {
  float u  = v * v;
  float m1 = 0.044715f * u;
  float w  = __builtin_fmaf(m1, v, v);             // v + 0.044715 v^3
  float e  = __builtin_amdgcn_exp2f(-2.3020575f * w); // exp2(-2*0.79788*L2E*w)
  float r  = __builtin_amdgcn_rcpf(1.0f + e);      // sigmoid
  float t  = 1.44269504f * v;
  return __builtin_fmaf(t, r, negm);               // L2E*gelu(v) + negm
}

__device__ __forceinline__ void gl2lds16(const void* g, void* l) {
  __builtin_amdgcn_global_load_lds(
      (const __attribute__((address_space(1))) void*)g,
      (__attribute__((address_space(3))) void*)l, 16, 0, 0);
}

__device__ __forceinline__ unsigned pkrtz(float a, float b) {
  auto t = __builtin_amdgcn_cvt_pkrtz(a, b);   // __fp16 ext_vector(2)
  return __builtin_bit_cast(unsigned, t);
}

// ---------------------------------------------------------------------------
// Kernel 0: one-time W1,W2 f32 -> f16 (scratch in d_out head; attn overwrites).
// ---------------------------------------------------------------------------
__global__ __launch_bounds__(256) void wcvt_kernel(
    const float* __restrict__ W1, const float* __restrict__ W2,
    _Float16* __restrict__ Wh1, _Float16* __restrict__ Wh2)
{
  int i = blockIdx.x * 256 + threadIdx.x;
  Wh1[i] = (_Float16)W1[i];
  Wh2[i] = (_Float16)W2[i];
}

// ---------------------------------------------------------------------------
// Kernel 1: q/k projections (f16 MFMA, f32 accum, +bias) and x -> V^T (f16).
// R17 keeper: float4 A-fragment loads + pkrtz. R19: transpose also pkrtz
// (16 pkrtz vs 32 scalar cvt per thread).
// ---------------------------------------------------------------------------
__global__ __launch_bounds__(256) void proj_tr_kernel(
    const float* __restrict__ x,
    const _Float16* __restrict__ Wh1, const float* __restrict__ b1,
    const _Float16* __restrict__ Wh2, const float* __restrict__ b2,
    _Float16* __restrict__ Qb, _Float16* __restrict__ Kb,
    _Float16* __restrict__ VT)
{
  const int tid  = threadIdx.x;
  const int wave = tid >> 6;
  const int lane = tid & 63;
  const int lhi  = lane >> 4;
  const int llo  = lane & 15;
  const int r0   = blockIdx.x * 64;
  const int wr0  = r0 + wave * 16;

  f16x8 a[4];
#pragma unroll
  for (int ks = 0; ks < 4; ++ks) {
    const f32x4* p = (const f32x4*)(x + (size_t)(wr0 + llo) * D_ + lhi * 8 + ks * 32);
    f32x4 f0 = p[0], f1 = p[1];
    union { unsigned u[4]; f16x8 v; } t;
    t.u[0] = pkrtz(f0[0], f0[1]);
    t.u[1] = pkrtz(f0[2], f0[3]);
    t.u[2] = pkrtz(f1[0], f1[1]);
    t.u[3] = pkrtz(f1[2], f1[3]);
    a[ks] = t.v;
  }

  f32x4 accq[8], acck[8];
#pragma unroll
  for (int n = 0; n < 8; ++n) {
    accq[n] = (f32x4){0.f, 0.f, 0.f, 0.f};
    acck[n] = (f32x4){0.f, 0.f, 0.f, 0.f};
  }

#pragma unroll
  for (int n = 0; n < 8; ++n) {
    const int e = n * 16 + llo;
#pragma unroll
    for (int ks = 0; ks < 4; ++ks) {
      f16x8 w1f = *(const f16x8*)(Wh1 + (size_t)e * D_ + lhi * 8 + ks * 32);
      f16x8 w2f = *(const f16x8*)(Wh2 + (size_t)e * D_ + lhi * 8 + ks * 32);
      accq[n] = __builtin_amdgcn_mfma_f32_16x16x32_f16(a[ks], w1f, accq[n], 0, 0, 0);
      acck[n] = __builtin_amdgcn_mfma_f32_16x16x32_f16(a[ks], w2f, acck[n], 0, 0, 0);
    }
  }

#pragma unroll
  for (int n = 0; n < 8; ++n) {
    const int e = n * 16 + llo;
    const float bias1 = b1[e];
    const float bias2 = b2[e];
#pragma unroll
    for (int r = 0; r < 4; ++r) {
      const size_t row = (size_t)wr0 + lhi * 4 + r;
      Qb[row * D_ + e] = (_Float16)(accq[n][r] + bias1);
      Kb[row * D_ + e] = (_Float16)(acck[n][r] + bias2);
    }
  }

  const int bh = r0 / L_;
  const int l0 = r0 % L_;
  const int d  = tid & 127;
  const int rh = tid >> 7;
  _Float16* dst = VT + (size_t)bh * D_ * L_ + (size_t)d * L_ + l0 + rh * 32;
#pragma unroll
  for (int j = 0; j < 4; ++j) {
    union { unsigned u[4]; f16x8 v; } t;
#pragma unroll
    for (int e = 0; e < 4; ++e) {
      float x0 = x[(size_t)(r0 + rh * 32 + j * 8 + 2 * e)     * D_ + d];
      float x1 = x[(size_t)(r0 + rh * 32 + j * 8 + 2 * e + 1) * D_ + d];
      t.u[e] = pkrtz(x0, x1);
    }
    *(f16x8*)(dst + j * 8) = t.v;
  }
}

// ---------------------------------------------------------------------------
// Kernel 2: fused gelu(QK^T)->softmax->@V flash attention, 32x32x16 MFMA.
// R16/R18 structure (best measured): K+V [128][128] supertiles, 16 barriers,
// 4-bit swizzle (conflicts=0), per-subtile softmax, deferred l-sum, T15,
// T12, defer-max. R19 delta: SPECULATIVE exp2 -- p=exp2(gm) issued before
// the max-tree + cross-half shuffle (independent in defer path, ~31/32
// tiles); rescale path becomes p*=sc (16 mults, cheaper than exp2+sub).
// R17 lesson: pair-merged softmax (32-float liveness) spills -> per-subtile.
// R14 lesson: NO cross-tile score pipelining (extra f32x16 sets spill).
// ---------------------------------------------------------------------------
__global__ __launch_bounds__(512) void attn_kernel(
    const _Float16* __restrict__ Qb, const _Float16* __restrict__ Kb,
    const _Float16* __restrict__ VT, float* __restrict__ out)
{
  __shared__ _Float16 Ks[2][128 * 128];   // 2 x 32KB, K supertile (128 k-rows)
  __shared__ _Float16 Vs[2][128 * 128];   // 2 x 32KB, V supertile (128 k)

  const int tid  = threadIdx.x;
  const int wave = tid >> 6;      // 0..7
  const int lane = tid & 63;
  const int l5   = lane & 31;
  const int hi   = lane >> 5;

  // XCD-aware swizzle: 512 blocks, 8 XCDs -> 8 whole heads per XCD.
  const int bid = blockIdx.x;
  const int blk = (bid & 7) * 64 + (bid >> 3);
  const int bh  = blk >> 3;            // 8 q-blocks (256 rows) per head
  const int q0  = (blk & 7) * 256;
  const int b   = bh >> 4;
  const int h   = bh & 15;
  const int wq0 = q0 + wave * 32;

  const char* KheadB = (const char*)(Kb + (size_t)bh * L_ * D_);
  const char* VheadB = (const char*)(VT + (size_t)bh * D_ * L_);

  // ---- staging constants: K and V supertiles, 4 calls x 8KB each ----
  int sdst[4], ksrc[4], vsrc[4];
#pragma unroll
  for (int c = 0; c < 4; ++c) {
    const int row = c * 32 + wave * 4 + (lane >> 4);    // 0..127
    const int c0  = (lane & 15) * 8;                    // col halves
    sdst[c] = c * 8192 + wave * 1024;                   // wave-uniform dest
    ksrc[c] = row * 256  + 2 * (c0 ^ ((row & 15) << 3)); // K row = 256B
    vsrc[c] = row * 4096 + 2 * (c0 ^ ((row & 15) << 3)); // V row = L*2B
  }
  const int swz4 = (l5 & 15) << 3;                      // read-side XOR (halves)

  // Q fragments (B-operand of swapped QK^T): j = l5 = q-row, k = s*16+hi*8+e
  f16x8 qf[8];
#pragma unroll
  for (int s = 0; s < 8; ++s)
    qf[s] = *(const f16x8*)(Qb + ((size_t)bh * L_ + wq0 + l5) * D_ + s * 16 + hi * 8);

  f32x16 accO[4];
#pragma unroll
  for (int n = 0; n < 4; ++n)
#pragma unroll
    for (int r = 0; r < 16; ++r) accO[n][r] = 0.f;
  float negm = 64.f;   // -m in exp2 units; m init -64 (synced across hi pair)
  float l = 0.f;       // per-half partial sum; combined once at epilogue

  // ---- prologue: stage K/V supertile 0 ----
#pragma unroll
  for (int c = 0; c < 4; ++c) {
    gl2lds16(KheadB + ksrc[c], (char*)&Ks[0][0] + sdst[c]);
    gl2lds16(VheadB + vsrc[c], (char*)&Vs[0][0] + sdst[c]);
  }
  __syncthreads();

  for (int ts = 0; ts < L_ / 128; ++ts) {   // 16 supertiles, 1 barrier each
    const int cur = ts & 1;
    // ---- prefetch next K/V supertile (in flight across 2 tile bodies) ----
    if (ts + 1 < L_ / 128) {
      const char* kt_ = KheadB + (size_t)(ts + 1) * 32768;
      const char* vt_ = VheadB + (size_t)(ts + 1) * 256;
#pragma unroll
      for (int c = 0; c < 4; ++c) {
        gl2lds16(kt_ + ksrc[c], (char*)&Ks[cur ^ 1][0] + sdst[c]);
        gl2lds16(vt_ + vsrc[c], (char*)&Vs[cur ^ 1][0] + sdst[c]);
      }
    }
    const _Float16* Vcur = &Vs[cur][0];

#pragma unroll
    for (int half = 0; half < 2; ++half) {   // two 64-k tiles per supertile
      const _Float16* Kcur = &Ks[cur][half * 64 * 128];
      const int vt0 = half * 64;             // k-offset in V supertile

      // ---- S^T for BOTH kb subtiles: two interleaved 8-deep chains ----
      f32x16 sA, sB;
#pragma unroll
      for (int r = 0; r < 16; ++r) { sA[r] = 0.f; sB[r] = 0.f; }
      __builtin_amdgcn_s_setprio(1);
#pragma unroll
      for (int s = 0; s < 8; ++s) {
        f16x8 kfa = *(const f16x8*)(Kcur + l5 * 128 +
                                    ((s * 16 + hi * 8) ^ swz4));
        sA = __builtin_amdgcn_mfma_f32_32x32x16_f16(kfa, qf[s], sA, 0, 0, 0);
        f16x8 kfb = *(const f16x8*)(Kcur + (32 + l5) * 128 +
                                    ((s * 16 + hi * 8) ^ swz4));
        sB = __builtin_amdgcn_mfma_f32_32x32x16_f16(kfb, qf[s], sB, 0, 0, 0);
      }
      __builtin_amdgcn_s_setprio(0);

      // ---- softmax + PV per subtile ----
      auto softmax_pv = [&](const f32x16& sT, int vkbase) {
        float gm[16];
#pragma unroll
        for (int r = 0; r < 16; ++r) gm[r] = gelu_m(sT[r], negm);

        // SPECULATIVE exp2: independent of tm; overlaps max tree + shuffle.
        // (max gm ~ 64+1.44*15 -> exp2 ~ 6e25, finite in f32.)
        float p[16];
#pragma unroll
        for (int r = 0; r < 16; ++r) p[r] = __builtin_amdgcn_exp2f(gm[r]);

        float tm = fmaxf(fmaxf(gm[0], gm[1]), gm[2]);
        tm = fmaxf(fmaxf(tm, gm[3]),  gm[4]);
        tm = fmaxf(fmaxf(tm, gm[5]),  gm[6]);
        tm = fmaxf(fmaxf(tm, gm[7]),  gm[8]);
        tm = fmaxf(fmaxf(tm, gm[9]),  gm[10]);
        tm = fmaxf(fmaxf(tm, gm[11]), gm[12]);
        tm = fmaxf(fmaxf(tm, gm[13]), gm[14]);
        tm = fmaxf(tm, gm[15]);
        tm = fmaxf(tm, __shfl_xor(tm, 32));   // REQUIRED: negm shared by pair

        if (!__all(tm <= 11.5415603f)) {      // rare (~1/32) rescale path
          float dm = fmaxf(tm, 0.f);
          negm -= dm;
          float sc = __builtin_amdgcn_exp2f(-dm);
#pragma unroll
          for (int r = 0; r < 16; ++r) p[r] *= sc;   // exp2(gm-dm) to rounding
          l *= sc;
          float scr[16];
#pragma unroll
          for (int r = 0; r < 16; ++r)
            scr[r] = __shfl(sc, (r & 3) + 8 * (r >> 2) + 4 * hi);
#pragma unroll
          for (int n = 0; n < 4; ++n)
#pragma unroll
            for (int r = 0; r < 16; ++r) accO[n][r] *= scr[r];
        }

        float a0 = p[0]+p[1],   a1 = p[2]+p[3],   a2 = p[4]+p[5],   a3 = p[6]+p[7];
        float a4 = p[8]+p[9],   a5 = p[10]+p[11], a6 = p[12]+p[13], a7 = p[14]+p[15];
        l += ((a0+a1)+(a2+a3)) + ((a4+a5)+(a6+a7));   // per-half partial

        // P -> PV A-fragments in-register (T12; distinct operands only)
        unsigned pk01 = pkrtz(p[0], p[1]),   pk23 = pkrtz(p[2], p[3]);
        unsigned pk45 = pkrtz(p[4], p[5]),   pk67 = pkrtz(p[6], p[7]);
        unsigned pk89 = pkrtz(p[8], p[9]),   pkAB = pkrtz(p[10], p[11]);
        unsigned pkCD = pkrtz(p[12], p[13]), pkEF = pkrtz(p[14], p[15]);
        u32x2 r0 = __builtin_amdgcn_permlane32_swap(pk01, pk45, false, false);
        u32x2 r1 = __builtin_amdgcn_permlane32_swap(pk23, pk67, false, false);
        u32x2 r2 = __builtin_amdgcn_permlane32_swap(pk89, pkCD, false, false);
        u32x2 r3 = __builtin_amdgcn_permlane32_swap(pkAB, pkEF, false, false);
        union { unsigned u[4]; f16x8 v; } A0c, A1c;
        A0c.u[0] = r0[0]; A0c.u[1] = r1[0]; A0c.u[2] = r0[1]; A0c.u[3] = r1[1];
        A1c.u[0] = r2[0]; A1c.u[1] = r3[0]; A1c.u[2] = r2[1]; A1c.u[3] = r3[1];

        // O += P @ V (V rows 128 halves in the supertile)
        __builtin_amdgcn_s_setprio(1);
#pragma unroll
        for (int n = 0; n < 4; ++n) {
          f16x8 vf0 = *(const f16x8*)(Vcur + (n * 32 + l5) * 128 +
                                      ((vkbase + hi * 8) ^ swz4));
          accO[n] = __builtin_amdgcn_mfma_f32_32x32x16_f16(A0c.v, vf0, accO[n], 0, 0, 0);
          f16x8 vf1 = *(const f16x8*)(Vcur + (n * 32 + l5) * 128 +
                                      ((vkbase + 16 + hi * 8) ^ swz4));
          accO[n] = __builtin_amdgcn_mfma_f32_32x32x16_f16(A1c.v, vf1, accO[n], 0, 0, 0);
        }
        __builtin_amdgcn_s_setprio(0);
      };

      softmax_pv(sA, vt0);
      softmax_pv(sB, vt0 + 32);
    }

    __syncthreads();   // one barrier per supertile (2 tiles); prefetch landed
  }

  // ---- epilogue: combine per-half l, then O[q][d] / l[q] ----
  l += __shfl_xor(l, 32);                    // the single cross-half l sum
  float linv = __builtin_amdgcn_rcpf(l);
  float lb[16];
#pragma unroll
  for (int r = 0; r < 16; ++r)
    lb[r] = __shfl(linv, (r & 3) + 8 * (r >> 2) + 4 * hi);
#pragma unroll
  for (int n = 0; n < 4; ++n)
#pragma unroll
    for (int r = 0; r < 16; ++r) {
      const int i = wq0 + (r & 3) + 8 * (r >> 2) + 4 * hi;
      out[((size_t)(b * L_ + i) * H_ + h) * D_ + n * 32 + l5] = accO[n][r] * lb[r];
    }
}

extern "C" void kernel_launch(void* const* d_in, const int* in_sizes, int n_in,
                              void* d_out, int out_size, void* d_ws, size_t ws_size,
                              hipStream_t stream) {
  const float* x  = (const float*)d_in[0];
  const float* W1 = (const float*)d_in[1];
  const float* b1 = (const float*)d_in[2];
  const float* W2 = (const float*)d_in[3];
  const float* b2 = (const float*)d_in[4];
  float* out = (float*)d_out;

  const size_t N = (size_t)BH_ * L_ * D_;
  _Float16* Qb = (_Float16*)d_ws;
  _Float16* Kb = Qb + N;
  _Float16* VT = Kb + N;

  _Float16* Wh1 = (_Float16*)d_out;          // scratch; attn overwrites out
  _Float16* Wh2 = Wh1 + D_ * D_;

  wcvt_kernel<<<64, 256, 0, stream>>>(W1, W2, Wh1, Wh2);
  proj_tr_kernel<<<(BH_ * L_) / 64, 256, 0, stream>>>(x, Wh1, b1, Wh2, b2, Qb, Kb, VT);
  attn_kernel<<<BH_ * (L_ / 256), 512, 0, stream>>>(Qb, Kb, VT, out);
}